// Round 7
// baseline (168.238 us; speedup 1.0000x reference)
//
#include <hip/hip_runtime.h>

#define DEVI __device__ __forceinline__

typedef short bf16x8 __attribute__((ext_vector_type(8)));
typedef float f32x4 __attribute__((ext_vector_type(4)));
typedef unsigned short u16;
typedef unsigned int u32;

// Problem constants
static constexpr int Bn = 2, S = 2048, E = 1024, H = 16, D = 64;
static constexpr int Mrows = Bn * S;          // 4096
static constexpr int N_QKV = 3 * E;           // 3072

DEVI u16 f2b(float f) {
  union { float f; u32 u; } c; c.f = f;
  return (u16)((c.u + 0x7FFFu + ((c.u >> 16) & 1u)) >> 16);
}

DEVI bf16x8 ld8(const u16* p) {
  union { uint4 u; bf16x8 v; } c;
  c.u = *reinterpret_cast<const uint4*>(p);
  return c.v;
}

#define MFMA(a, b, c) __builtin_amdgcn_mfma_f32_16x16x32_bf16(a, b, c, 0, 0, 0)

// global -> LDS async copy, 16B per lane. LDS dest must be wave-uniform-base + lane*16.
#define G2L16(gptr, lptr) \
  __builtin_amdgcn_global_load_lds((const __attribute__((address_space(1))) void*)(gptr), \
                                   (__attribute__((address_space(3))) void*)(lptr), 16, 0, 0)

// ---------------- Fused prep: transposes FIRST, conv LAST (r14 order) ----------------
__global__ __launch_bounds__(256) void prep(const float* __restrict__ x,
                                            const float* __restrict__ w_attn,
                                            const float* __restrict__ w_proj,
                                            u16* __restrict__ xb, u16* __restrict__ wabT,
                                            u16* __restrict__ wpbT) {
  __shared__ float t[32][33];
  int blk = blockIdx.x, tid = threadIdx.x;
  if (blk >= 4096) {
    int i = (blk - 4096) * 256 + tid;          // n4 = 4096*1024/4 = 1048576
    float4 f = reinterpret_cast<const float4*>(x)[i];
    ushort4 u;
    u.x = f2b(f.x); u.y = f2b(f.y); u.z = f2b(f.z); u.w = f2b(f.w);
    reinterpret_cast<ushort4*>(xb)[i] = u;
    return;
  }
  const float* in; u16* out; int R, C, bx, by;
  if (blk < 3072) {
    in = w_attn; out = wabT; R = E; C = N_QKV;  // 96 x 32 tiles
    bx = (blk % 96) * 32; by = (blk / 96) * 32;
  } else {
    int q = blk - 3072;                         // 32 x 32 tiles
    in = w_proj; out = wpbT; R = E; C = E;
    bx = (q % 32) * 32; by = (q / 32) * 32;
  }
  int tx = tid & 31, ty = tid >> 5;             // 32 x 8
#pragma unroll
  for (int k = 0; k < 32; k += 8)
    t[ty + k][tx] = in[(size_t)(by + ty + k) * C + bx + tx];
  __syncthreads();
#pragma unroll
  for (int k = 0; k < 32; k += 8)
    out[(size_t)(bx + ty + k) * R + by + tx] = f2b(t[tx][ty + k]);
}

// ---------------- GEMM1: qkv = xb @ wabT^T, 128x64 tile, BK=64, XOR swizzle ----------
// r23: OPERAND-SWAPPED MFMA for Q/K-section blocks. Issue-slot arithmetic: the old
// per-element scatter (32 scalar u16 stores/thread for Q/K blocks) cost ~13.6us of
// store-issue per SIMD. MFMA(b,a) computes D^T: lane mapping becomes row=l15 (m),
// cols=quad*4+r = 4 CONSECUTIVE n = 4 consecutive d at fixed s -> ushort4 stores
// (32 -> 8 insts/thread). A/B frag layouts are identical for 16x16x32 (lane l: row
// l&15, k-slice (l>>4)*8) so the swap is pure relabeling. V-section keeps unswapped
// order (its d-major ushort4 already exploits 4-consecutive-s). Branch is block-
// uniform (n0 < 2048). Q pre-scaled by log2e/8 (attn scores arrive in log2 domain).
__global__ __launch_bounds__(256) void gemm_qkv(const u16* __restrict__ A, const u16* __restrict__ BT,
                                                u16* __restrict__ Qb, u16* __restrict__ Kb,
                                                u16* __restrict__ VbT) {
  constexpr int K = 1024, BK = 64;
  __shared__ __align__(16) u16 As[128 * BK];   // 16 KB, swizzled rows of 8 16B-groups
  __shared__ __align__(16) u16 Bs[64 * BK];    // 8 KB
  int tid = threadIdx.x;
  int w = tid >> 6, lane = tid & 63, quad = lane >> 4, l15 = lane & 15;
  int m0 = blockIdx.x * 128, n0 = blockIdx.y * 64;
  int mw = (w >> 1) * 64, nw = (w & 1) * 32;   // wave-tile 64x32
  const bool qk = (n0 < 2048);                 // Q or K section -> swapped operands
  const u16* Ab = A + (size_t)m0 * K;
  const u16* Bb = BT + (size_t)n0 * K;
  f32x4 acc[4][2] = {};
  for (int k0 = 0; k0 < K; k0 += BK) {
#pragma unroll
    for (int j = 0; j < 4; j++) {
      int L = j * 256 + tid;
      int row = L >> 3, cg = (L & 7) ^ (row & 7);
      G2L16(Ab + (size_t)row * K + k0 + cg * 8, (char*)As + L * 16);
    }
#pragma unroll
    for (int j = 0; j < 2; j++) {
      int L = j * 256 + tid;
      int row = L >> 3, cg = (L & 7) ^ (row & 7);
      G2L16(Bb + (size_t)row * K + k0 + cg * 8, (char*)Bs + L * 16);
    }
    __syncthreads();
#pragma unroll
    for (int kk = 0; kk < 2; kk++) {
      int sg = ((kk << 2) | quad) ^ (l15 & 7);   // swizzled 16B-group for this lane
      bf16x8 a[4], b[2];
#pragma unroll
      for (int i = 0; i < 4; i++) a[i] = ld8(&As[(mw + i * 16 + l15) * BK + sg * 8]);
#pragma unroll
      for (int i = 0; i < 2; i++) b[i] = ld8(&Bs[(nw + i * 16 + l15) * BK + sg * 8]);
      if (qk) {
#pragma unroll
        for (int mb = 0; mb < 4; mb++)
#pragma unroll
          for (int nb = 0; nb < 2; nb++)
            acc[mb][nb] = MFMA(b[nb], a[mb], acc[mb][nb]);   // D^T: row=l15(m), col=quad*4+r(n)
      } else {
#pragma unroll
        for (int mb = 0; mb < 4; mb++)
#pragma unroll
          for (int nb = 0; nb < 2; nb++)
            acc[mb][nb] = MFMA(a[mb], b[nb], acc[mb][nb]);   // row=quad*4+r(m), col=l15(n)
      }
    }
    __syncthreads();
  }
  int h = (n0 & 1023) >> 6;                    // head: block-constant (64-wide tile in one head)
  if (qk) {
    // ---- Q/K sections: lane holds 4 consecutive d at fixed row s -> ushort4 ----
    int sec = n0 >> 10;                        // 0=Q, 1=K
#pragma unroll
    for (int mb = 0; mb < 4; mb++) {
      int m = m0 + mw + mb * 16 + l15;         // tiles never straddle batch
      int b = m >> 11, s = m & 2047;
      int bh = b * H + h;
      u16* dst = (sec == 0 ? Qb : Kb) + ((size_t)bh * S + s) * D;
#pragma unroll
      for (int nb = 0; nb < 2; nb++) {
        int d0 = nw + nb * 16 + quad * 4;      // n0 is 64-aligned -> d = d0 + r
        ushort4 v;
        if (sec == 0) {
          v.x = f2b(acc[mb][nb][0] * 0.1803368801111244f);
          v.y = f2b(acc[mb][nb][1] * 0.1803368801111244f);
          v.z = f2b(acc[mb][nb][2] * 0.1803368801111244f);
          v.w = f2b(acc[mb][nb][3] * 0.1803368801111244f);
        } else {
          v.x = f2b(acc[mb][nb][0]); v.y = f2b(acc[mb][nb][1]);
          v.z = f2b(acc[mb][nb][2]); v.w = f2b(acc[mb][nb][3]);
        }
        *reinterpret_cast<ushort4*>(dst + d0) = v;
      }
    }
  } else {
    // ---- V section: lane holds 4 consecutive s at fixed d -> d-major ushort4 ----
#pragma unroll
    for (int mb = 0; mb < 4; mb++) {
      int m = m0 + mw + mb * 16 + quad * 4;
      int b = m >> 11, s = m & 2047;
      int bh = b * H + h;
#pragma unroll
      for (int nb = 0; nb < 2; nb++) {
        int d = nw + nb * 16 + l15;
        ushort4 v;
        v.x = f2b(acc[mb][nb][0]); v.y = f2b(acc[mb][nb][1]);
        v.z = f2b(acc[mb][nb][2]); v.w = f2b(acc[mb][nb][3]);
        *reinterpret_cast<ushort4*>(VbT + ((size_t)bh * D + d) * S + s) = v;
      }
    }
  }
}

// ---------------- Flash attention: r0 VERBATIM (best-known: 43.6us) ----------------
// Ledger: r0 (128-key chunk, single-buf, LDS-P, 3/CU, heavy-first) = 43.6 BEST;
// r19 P-slice 50.4; r20 dbuf-64+vmcnt 49.6; r21 reg-P-64 51.9; r22 reg-P-128 46.7.
// r22's conflicts (4.26M, identical to r21) prove the register-P b64 V-read is
// inherently 4-way bank-conflicted (~7us/CU) regardless of tile width; and exact-
// co-resident balanced scheduling has a 2x makespan tail vs heavy-first+backfill.
// attn is a local optimum at this structure -- frozen at r0.
__global__ __launch_bounds__(256, 3) void attn(const u16* __restrict__ Qb, const u16* __restrict__ Kb,
                                               const u16* __restrict__ VbT, u16* __restrict__ Yb) {
  __shared__ __align__(16) u16 Ks[128 * 64];    // swizzled: (row, cg) at row*64 + (cg^(row&7))*8
  __shared__ __align__(16) u16 Vs[64 * 128];    // swizzled: (d, cg) at d*128 + (cg^(d&15))*8
  __shared__ __align__(16) u32 Ps[4][16 * 68];  // per-wave P[q=16][k=128] bf16, stride 68 u32
  int w = threadIdx.x >> 6, lane = threadIdx.x & 63, quad = lane >> 4, l15 = lane & 15;
  int bh = blockIdx.x & 31, qt = 31 - (blockIdx.x >> 5);   // heavy q-tiles first
  int b = bh >> 4, h = bh & 15;
  int nc = (qt + 2) >> 1;            // staged 128-key chunks

  const u16* Kbh = Kb + (size_t)bh * S * D;
  const u16* Vbh = VbT + (size_t)bh * D * S;
  u32* myP = &Ps[w][0];
  const u16* myP16 = (const u16*)myP;
  int prow = l15 * 68 + quad * 2;    // u32 index for this lane's P writes

  int q_base = qt * 64 + w * 16;
  int qrow = q_base + l15;
  int kmax = q_base + 16;            // causal: this wave needs keys [0, kmax)

  const u16* Qp = Qb + ((size_t)bh * S + qrow) * D + quad * 8;
  bf16x8 bq0 = ld8(Qp), bq1 = ld8(Qp + 32);

  float lpart = 0.f;
  f32x4 o[4] = {};

  for (int c = 0; c < nc; c++) {
    int kbase = c * 128;
    __syncthreads();                 // previous chunk's readers done
    // ---- cooperative staging: K tile (16KB) ----
    const u16* Kg = Kbh + (size_t)kbase * D;
#pragma unroll
    for (int j = 0; j < 4; j++) {
      int L = (w * 4 + j) * 64 + lane;
      int row = L >> 3, cg = (L & 7) ^ (row & 7);
      G2L16(Kg + (size_t)row * 64 + cg * 8, (char*)Ks + L * 16);
    }
    // ---- cooperative staging: V^T tile (16KB) ----
    const u16* Vg = Vbh + kbase;
#pragma unroll
    for (int j = 0; j < 4; j++) {
      int L = (w * 4 + j) * 64 + lane;
      int row = L >> 4, cg = (L & 15) ^ (row & 15);
      G2L16(Vg + (size_t)row * S + cg * 8, (char*)Vs + L * 16);
    }
    __syncthreads();                 // staging visible (barrier drains vmcnt)

    // ---- QK^T + exp2 + perm-pack into wave-private P ----
#pragma unroll
    for (int mb = 0; mb < 8; mb++) {
      int kb = kbase + mb * 16;
      u32 pa = 0, pb = 0;
      if (kb < kmax) {               // wave-uniform
        int row = mb * 16 + l15;
        bf16x8 ak0 = ld8(&Ks[row * 64 + ((quad ^ (row & 7)) * 8)]);
        bf16x8 ak1 = ld8(&Ks[row * 64 + (((quad + 4) ^ (row & 7)) * 8)]);
        f32x4 z = {};
        z = MFMA(ak0, bq0, z);
        z = MFMA(ak1, bq1, z);
        if (kb == q_base) {          // diagonal subtile: mask k > q
#pragma unroll
          for (int r = 0; r < 4; r++)
            if (quad * 4 + r > l15) z[r] = -1e30f;
        }
        float p0 = __builtin_amdgcn_exp2f(z[0]);
        float p1 = __builtin_amdgcn_exp2f(z[1]);
        float p2 = __builtin_amdgcn_exp2f(z[2]);
        float p3 = __builtin_amdgcn_exp2f(z[3]);
        lpart += (p0 + p1) + (p2 + p3);
        union { float f; u32 u; } c0, c1, c2, c3;
        c0.f = p0; c1.f = p1; c2.f = p2; c3.f = p3;
        pa = __builtin_amdgcn_perm(c1.u + 0x8000u, c0.u + 0x8000u, 0x07060302u);
        pb = __builtin_amdgcn_perm(c3.u + 0x8000u, c2.u + 0x8000u, 0x07060302u);
      }
      uint2 pw; pw.x = pa; pw.y = pb;
      *reinterpret_cast<uint2*>(&myP[prow + mb * 8]) = pw;   // ds_write_b64
    }
    // ---- O^T += V^T · P^T per 32-key chunk ----
#pragma unroll
    for (int ch = 0; ch < 4; ch++) {
      if (kbase + ch * 32 < kmax) {  // wave-uniform
        bf16x8 bp = ld8(myP16 + l15 * 136 + ch * 32 + quad * 8);
#pragma unroll
        for (int dd = 0; dd < 4; dd++) {
          int rv = dd * 16 + l15;
          bf16x8 av = ld8(&Vs[rv * 128 + (((ch * 4 + quad) ^ (rv & 15)) * 8)]);
          o[dd] = MFMA(av, bp, o[dd]);
        }
      }
    }
  }

  // ---- epilogue: each wave owns the full k-range of its 16 q-rows ----
  float l = lpart;
  l += __shfl_xor(l, 16);
  l += __shfl_xor(l, 32);
  float rinv = 1.0f / l;
  u16* Yp = Yb + ((size_t)b * S + qrow) * E + h * 64 + quad * 4;
#pragma unroll
  for (int dd = 0; dd < 4; dd++) {
    ushort4 y;
    y.x = f2b(o[dd][0] * rinv); y.y = f2b(o[dd][1] * rinv);
    y.z = f2b(o[dd][2] * rinv); y.w = f2b(o[dd][3] * rinv);
    *reinterpret_cast<ushort4*>(Yp + dd * 16) = y;
  }
}

// ---------------- GEMM2: out = Yb @ wpbT^T, 128x64 tile, SWAPPED operands (r23) -------
// MFMA(b,a) = D^T: lane holds row m=l15, 4 consecutive n=quad*4+r -> float4 stores
// (32 scalar dwords -> 8 dwordx4 per thread; ~6.8us/SIMD of store-issue removed).
__global__ __launch_bounds__(256) void gemm_proj(const u16* __restrict__ A, const u16* __restrict__ BT,
                                                 float* __restrict__ out) {
  constexpr int K = 1024, BK = 64;
  __shared__ __align__(16) u16 As[128 * BK];   // 16 KB
  __shared__ __align__(16) u16 Bs[64 * BK];    // 8 KB
  int tid = threadIdx.x;
  int w = tid >> 6, lane = tid & 63, quad = lane >> 4, l15 = lane & 15;
  int m0 = blockIdx.x * 128, n0 = blockIdx.y * 64;
  int mw = (w >> 1) * 64, nw = (w & 1) * 32;
  const u16* Ab = A + (size_t)m0 * K;
  const u16* Bb = BT + (size_t)n0 * K;
  f32x4 acc[4][2] = {};
  for (int k0 = 0; k0 < K; k0 += BK) {
#pragma unroll
    for (int j = 0; j < 4; j++) {
      int L = j * 256 + tid;
      int row = L >> 3, cg = (L & 7) ^ (row & 7);
      G2L16(Ab + (size_t)row * K + k0 + cg * 8, (char*)As + L * 16);
    }
#pragma unroll
    for (int j = 0; j < 2; j++) {
      int L = j * 256 + tid;
      int row = L >> 3, cg = (L & 7) ^ (row & 7);
      G2L16(Bb + (size_t)row * K + k0 + cg * 8, (char*)Bs + L * 16);
    }
    __syncthreads();
#pragma unroll
    for (int kk = 0; kk < 2; kk++) {
      int sg = ((kk << 2) | quad) ^ (l15 & 7);
      bf16x8 a[4], b[2];
#pragma unroll
      for (int i = 0; i < 4; i++) a[i] = ld8(&As[(mw + i * 16 + l15) * BK + sg * 8]);
#pragma unroll
      for (int i = 0; i < 2; i++) b[i] = ld8(&Bs[(nw + i * 16 + l15) * BK + sg * 8]);
#pragma unroll
      for (int mb = 0; mb < 4; mb++)
#pragma unroll
        for (int nb = 0; nb < 2; nb++)
          acc[mb][nb] = MFMA(b[nb], a[mb], acc[mb][nb]);   // D^T: row=l15(m), col=quad*4+r(n)
    }
    __syncthreads();
  }
#pragma unroll
  for (int mb = 0; mb < 4; mb++) {
    int m = m0 + mw + mb * 16 + l15;
#pragma unroll
    for (int nb = 0; nb < 2; nb++) {
      int n = n0 + nw + nb * 16 + quad * 4;
      float4 v;
      v.x = acc[mb][nb][0]; v.y = acc[mb][nb][1];
      v.z = acc[mb][nb][2]; v.w = acc[mb][nb][3];
      *reinterpret_cast<float4*>(&out[(size_t)m * E + n]) = v;
    }
  }
}

extern "C" void kernel_launch(void* const* d_in, const int* in_sizes, int n_in,
                              void* d_out, int out_size, void* d_ws, size_t ws_size,
                              hipStream_t stream) {
  const float* x = (const float*)d_in[0];
  const float* w_attn = (const float*)d_in[1];
  const float* w_proj = (const float*)d_in[2];
  float* out = (float*)d_out;
  char* ws = (char*)d_ws;

  // workspace layout (bytes)
  u16* xb   = (u16*)(ws);                      // 4096*1024*2 = 8 MB
  u16* wabT = (u16*)(ws + 8388608);            // 3072*1024*2 = 6 MB
  u16* wpbT = (u16*)(ws + 14680064);           // 1024*1024*2 = 2 MB
  u16* Qb   = (u16*)(ws + 16777216);           // 8 MB
  u16* Kb   = (u16*)(ws + 25165824);           // 8 MB
  u16* VbT  = (u16*)(ws + 33554432);           // 8 MB
  u16* Yb   = (u16*)(ws + 41943040);           // 8 MB   (total 48 MB)

  prep<<<8192, 256, 0, stream>>>(x, w_attn, w_proj, xb, wabT, wpbT);
  gemm_qkv<<<dim3(Mrows / 128, N_QKV / 64), 256, 0, stream>>>(xb, wabT, Qb, Kb, VbT);
  attn<<<Bn * H * (S / 64), 256, 0, stream>>>(Qb, Kb, VbT, Yb);
  gemm_proj<<<dim3(Mrows / 128, E / 64), 256, 0, stream>>>(Yb, wpbT, out);
}